// Round 10
// baseline (183.794 us; speedup 1.0000x reference)
//
#include <hip/hip_runtime.h>

#define NN 400
#define HID 96
#define EDGES 79800
#define BATCH 16
#define ROWS (BATCH*EDGES)
#define NT 13            // node tiles of 32 (tile 12 half-padded)
#define NPAIRS 91        // NT*(NT+1)/2

typedef _Float16 f16;
typedef f16 f16x2 __attribute__((ext_vector_type(2)));
typedef f16 f16x8 __attribute__((ext_vector_type(8)));
typedef __fp16 fp16x2 __attribute__((ext_vector_type(2)));
typedef float f32x16 __attribute__((ext_vector_type(16)));
typedef unsigned int u32;
typedef unsigned long long u64;

union H8 { f16x8 h; u32 u[4]; f16x2 p[4]; fp16x2 q[4]; u64 d[2]; };
union C2 { f16x2 h; fp16x2 q; u32 u; };

__device__ inline f16x2 pkrtz(float a, float b) {
  C2 c; c.q = __builtin_amdgcn_cvt_pkrtz(a, b); return c.h;
}
__device__ inline u32 pkrtz_u(float a, float b) {
  C2 c; c.q = __builtin_amdgcn_cvt_pkrtz(a, b); return c.u;
}
__device__ inline float fdot2a(f16x2 a, f16x2 b, float c) {
#if __has_builtin(__builtin_amdgcn_fdot2)
  C2 ca, cb; ca.h = a; cb.h = b;
  return __builtin_amdgcn_fdot2(ca.q, cb.q, c, false);
#else
  return c + (float)a.x*(float)b.x + (float)a.y*(float)b.y;
#endif
}

__device__ inline f16x8 habs8(f16x8 x) {
  H8 t; t.h = x;
  t.u[0] &= 0x7fff7fffu; t.u[1] &= 0x7fff7fffu;
  t.u[2] &= 0x7fff7fffu; t.u[3] &= 0x7fff7fffu;
  return t.h;
}

__device__ inline f16x8 pack8(float a0,float a1,float a2,float a3,
                              float a4,float a5,float a6,float a7){
  H8 u;
  u.p[0] = pkrtz(a0,a1);
  u.p[1] = pkrtz(a2,a3);
  u.p[2] = pkrtz(a4,a5);
  u.p[3] = pkrtz(a6,a7);
  return u.h;
}

// v_permlane32_swap_b32: vdst.hi32lanes <-> vsrc.lo32lanes.
__device__ inline void plswap(u32 &x, u32 &y) {
  auto r = __builtin_amdgcn_permlane32_swap((int)x, (int)y, false, false);
  x = (u32)r[0]; y = (u32)r[1];
}

// Aliasing fence: stops LICM/scheduler from hoisting+clustering loop-invariant LDS reads
// (the R2-R4 spill source). Register-only ops (MFMA, packs) are unaffected.
#define MEMFENCE asm volatile("" ::: "memory")

// ---------------- fused prep (blocks 0..139) + per-batch partial mean (blocks 140..395) --------
// wq regions (dwords): Wd1 [0,9216)  Wd2 plain-K [9216,11264)  We1 [11264,31232)  We2 [31232,35840)
__global__ void prep_mean_kernel(const float* __restrict__ We1, const float* __restrict__ We2,
                                 const float* __restrict__ W1, const float* __restrict__ W2,
                                 const float* __restrict__ sc,
                                 u32* __restrict__ wq, float* __restrict__ mpart) {
  if (blockIdx.x >= 140) {
    int p = blockIdx.x - 140;           // 0..255
    int b = p >> 4, part = p & 15;
    const float4* src = (const float4*)(sc + (size_t)b*160000) + part*2500;
    float s = 0.f;
    for (int i = threadIdx.x; i < 2500; i += 256) {
      float4 v = src[i];
      s += (v.x + v.y) + (v.z + v.w);
    }
    __shared__ float red[256];
    red[threadIdx.x] = s; __syncthreads();
    for (int off = 128; off > 0; off >>= 1) {
      if (threadIdx.x < off) red[threadIdx.x] += red[threadIdx.x + off];
      __syncthreads();
    }
    if (threadIdx.x == 0) mpart[p] = red[0];
    return;
  }
  int D = blockIdx.x*256 + threadIdx.x;     // 0..35839
  float v0, v1;
  if (D < 9216) {               // W_d1 frags (288 x 64), d = 32q+c  (A-frag == B-frag layout)
    int frag = D >> 8;  int t = frag >> 1, q = frag & 1;
    int rem = D & 255;  int lane = rem >> 2, dj = rem & 3;
    int c = lane & 31, h2 = lane >> 5;
    int k = 16*t + 8*h2 + 2*dj;
    int d = 32*q + c;
    v0 = W1[k*64 + d]; v1 = W1[(k+1)*64 + d];
  } else if (D < 11264) {       // W_d2 frags, PLAIN K (A-frags for swapped layer-2)
    int Dl = D - 9216;
    int frag = Dl >> 8; int t2 = frag >> 1, q = frag & 1;
    int rem = Dl & 255; int lane = rem >> 2, dj = rem & 3;
    int c = lane & 31, h2 = lane >> 5;
    int k = 16*t2 + 8*h2 + 2*dj;
    int d = 32*q + c;
    v0 = W2[k*64 + d]; v1 = W2[(k+1)*64 + d];
  } else if (D < 31232) {       // W_e1 frags (416 x 96), sc features first, static at 400
    int Dl = D - 11264;
    int frag = Dl >> 8; int t = frag/3, ct = frag - 3*t;
    int rem = Dl & 255; int lane = rem >> 2, dj = rem & 3;
    int c = lane & 31, h2 = lane >> 5;
    int k0 = 16*t + 8*h2 + 2*dj, k1 = k0 + 1;
    int d = 32*ct + c;
    v0 = (k0 < 400) ? We1[(8+k0)*96 + d] : (k0 < 408 ? We1[(k0-400)*96 + d] : 0.f);
    v1 = (k1 < 400) ? We1[(8+k1)*96 + d] : (k1 < 408 ? We1[(k1-400)*96 + d] : 0.f);
  } else {                      // W_e2 frags (96 x 96), plain K order
    int Dl = D - 31232;
    int frag = Dl >> 8; int t = frag/3, ct = frag - 3*t;
    int rem = Dl & 255; int lane = rem >> 2, dj = rem & 3;
    int c = lane & 31, h2 = lane >> 5;
    int k = 16*t + 8*h2 + 2*dj;
    int d = 32*ct + c;
    v0 = We2[k*96 + d]; v1 = We2[(k+1)*96 + d];
  }
  wq[D] = pkrtz_u(v0, v1);
}

// ---------------- encoder v2: per-wave full-K, 2 barriers, zero combine (R9, kept) ------------
__global__ __launch_bounds__(256) void enc_kernel(
    const float* __restrict__ sc, const float* __restrict__ nf,
    const float* __restrict__ smean, const float* __restrict__ sstd,
    const float* __restrict__ be1, const float* __restrict__ ae1,
    const float* __restrict__ be2, const float* __restrict__ ae2,
    const float* __restrict__ mpart, const u32* __restrict__ wq,
    f16* __restrict__ hout) {
  __shared__ u32 lds[6720 + 1600];
  const int tid = threadIdx.x;
  const int wid = tid >> 6, lane = tid & 63;
  const int c = lane & 31, h2 = lane >> 5;
  const int r0 = blockIdx.x * 32;
  // Phase A: stage normalized sc rows as f16 (all waves)
  {
    int row = tid >> 3, seg = tid & 7;
    int r = r0 + row;
    int b = r / 400;
    float ms = 0.f;
    const float4* mp4 = (const float4*)(mpart + 16*b);
#pragma unroll
    for (int k = 0; k < 4; ++k) { float4 v = mp4[k]; ms += (v.x+v.y)+(v.z+v.w); }
    float rm = 1.f / fmaxf(ms*(1.f/160000.f), 1e-8f);
    const float4* src = (const float4*)(sc + (size_t)r*400);
#pragma unroll
    for (int i = 0; i < 13; ++i) {
      int col4 = seg + 8*i;
      if (col4 < 100) {
        float4 v = src[col4];
        u32 lo = pkrtz_u(v.x*rm, v.y*rm);
        u32 hi = pkrtz_u(v.z*rm, v.w*rm);
        *(u64*)(lds + row*210 + col4*2) = (u64)lo | ((u64)hi << 32);
      }
    }
  }
  // weight preload (per-wave ct) + static-feature frag: independent of LDS staging,
  // issued before the barrier so the global latency hides under staging.
  f16x8 bfr[26], we2r[6], af25;
  if (wid < 3) {
    const u32* wb1 = wq + 11264;
#pragma unroll
    for (int t = 0; t < 26; ++t)
      bfr[t] = *(const f16x8*)(wb1 + ((t*3+wid)*64 + lane)*4);
    const u32* wb2 = wq + 31232;
#pragma unroll
    for (int t = 0; t < 6; ++t)
      we2r[t] = *(const f16x8*)(wb2 + ((t*3+wid)*64 + lane)*4);
    af25 = (f16x8){};
    if (h2 == 0) {
      int r = r0 + c;
      float q0[8];
#pragma unroll
      for (int j = 0; j < 8; ++j)
        q0[j] = (nf[r*8 + j] - smean[j]) / (sstd[j] + 1e-8f);
      af25 = pack8(q0[0],q0[1],q0[2],q0[3],q0[4],q0[5],q0[6],q0[7]);
    }
  }
  __syncthreads();
  f16* zb16 = (f16*)(lds + 6720);
  if (wid < 3) {
    const float a1 = *ae1;
    float bv = be1[32*wid + c];
    f32x16 acc;
#pragma unroll
    for (int i = 0; i < 16; ++i) acc[i] = bv;
#pragma unroll
    for (int t = 0; t < 25; ++t) {
      H8 av;
      const u32* ap = lds + c*210 + 8*t + 4*h2;
      av.d[0] = *(const u64*)ap;
      av.d[1] = *(const u64*)(ap + 2);
      acc = __builtin_amdgcn_mfma_f32_32x32x16_f16(av.h, bfr[t], acc, 0,0,0);
    }
    acc = __builtin_amdgcn_mfma_f32_32x32x16_f16(af25, bfr[25], acc, 0,0,0);
#pragma unroll
    for (int r = 0; r < 16; ++r) {
      float v = acc[r]; v = fmaxf(v, a1*v);
      int row = (r & 3) + 8*(r >> 2) + 4*h2;
      zb16[row*100 + 32*wid + c] = (f16)v;
    }
  }
  __syncthreads();
  if (wid < 3) {
    const float a2 = *ae2;
    float bv = be2[32*wid + c];
    f32x16 acc2;
#pragma unroll
    for (int i = 0; i < 16; ++i) acc2[i] = bv;
#pragma unroll
    for (int t = 0; t < 6; ++t) {
      f16x8 af = *(const f16x8*)(zb16 + c*100 + 16*t + 8*h2);
      acc2 = __builtin_amdgcn_mfma_f32_32x32x16_f16(af, we2r[t], acc2, 0,0,0);
    }
#pragma unroll
    for (int rr = 0; rr < 16; ++rr) {
      int row = (rr & 3) + 8*(rr >> 2) + 4*h2;
      float v = acc2[rr]; v = fmaxf(v, a2*v);
      hout[(r0 + row)*96 + 32*wid + c] = (f16)v;
    }
  }
}

// ---------------- decoder v9: m-SEQUENTIAL + fences at 3 blocks/CU ----------------
// R5-R9 ledger: fences fix spilling (FETCH 4.7MB) but 2 blocks/CU caps combined issue at
// MfmaUtil 40 + VALUBusy 37 (1:1 VALU:MFMA mix). R6: 3 blocks beat 2 even WITH mild spill.
// v9 = R3's m-sequential structure (correctness-proven) + R5's fences: peak regs ~150
// (acc[2]=32, zacc overlaps only w[16], weight window <=24, hjr 24, persistents ~78) under
// the (256,3) ~168 cap. Cost: weight ds_reads not shared across m (+36 b128/it) — hidden
// by the 3rd wave's TLP. LDS 51,200 B x 3 = 153,600 <= 163,840.
__global__ __launch_bounds__(256, 3) void decoder_kernel(
    const f16* __restrict__ hbuf, const u32* __restrict__ wq,
    const float* __restrict__ b1, const float* __restrict__ b2,
    const float* __restrict__ ad1, const float* __restrict__ ad2,
    const float* __restrict__ W3, const float* __restrict__ b3p,
    float* __restrict__ out) {
  __shared__ alignas(16) u32 smem[12800];
  const int tid = threadIdx.x;
  // task decode
  int p = blockIdx.x;
  int b = p / NPAIRS, pr = p - b*NPAIRS;
  int I = 0;
  while (pr >= NT - I) { pr -= NT - I; ++I; }
  const int J = I + pr;
  // stage hI rows: 32 rows x 48 dwords (clamped for tile 12)
  for (int i = tid; i < 384; i += 256) {
    int row = i / 12, off = i - row*12;
    int nb = I*32 + row; nb = nb < NN ? nb : NN-1;
    const float4* src = (const float4*)(hbuf + (size_t)(b*NN + nb)*HID) + off;
    *((float4*)(smem + row*48) + off) = *src;
  }
  // stage Wd1 (9216 dw) + Wd2 (2048 dw) contiguously
  {
    float4* dst = (float4*)(smem + 1536);
    const float4* srcw = (const float4*)wq;
    for (int i = tid; i < 2816; i += 256) dst[i] = srcw[i];
  }

  const int lane = tid & 63;
  const int wid  = tid >> 6;
  const int c = lane & 31, h2 = lane >> 5;
  const int gj = J*32 + c;
  const int gjc = gj < NN ? gj : NN-1;
  // hj frags for this lane's edge column, loop-invariant -> registers (from global, L2-hot)
  f16x8 hjr[6];
  {
    const f16* hjp = hbuf + (size_t)(b*NN + gjc)*HID + 8*h2;
#pragma unroll
    for (int t = 0; t < 6; ++t) hjr[t] = *(const f16x8*)(hjp + 16*t);
  }
  const float a1 = *ad1, a2 = *ad2, b3 = *b3p;
  const f16x2 a1v = pkrtz(a1, a1);
  const f16x2 a2v = pkrtz(a2, a2);
  // bias MFMA operands: B = const-1 frag (k-slot 0 of the extra kstep), A = bias column
  f16x8 bcst = (f16x8){};
  f16x8 ab1f[2]; ab1f[0] = (f16x8){}; ab1f[1] = (f16x8){};
  f16x8 ab2f[2]; ab2f[0] = (f16x8){}; ab2f[1] = (f16x8){};
  if (h2 == 0) {
    bcst[0] = (f16)1.f;
    ab1f[0][0] = (f16)b1[c];      ab1f[1][0] = (f16)b1[32 + c];
    ab2f[0][0] = (f16)b2[c];      ab2f[1][0] = (f16)b2[32 + c];
  }
  // W3 packed per-lane pairs matching acc row layout
  f16x2 w3q[2][8];
#pragma unroll
  for (int q2 = 0; q2 < 2; ++q2)
#pragma unroll
    for (int a = 0; a < 8; ++a) {
      int base = 32*q2 + 8*(a >> 1) + 2*(a & 1) + 4*h2;
      w3q[q2][a] = pkrtz(W3[base], W3[base + 1]);
    }
  __syncthreads();

  const f16* hIb = (const f16*)smem;
  const u32* wfr = smem + 1536;
  const u32* w2a = smem + 10752;
  const int bofs = b*EDGES;

#pragma unroll 1
  for (int it = 0; it < 4; ++it) {
#pragma unroll 1
    for (int m = 0; m < 2; ++m) {
      MEMFENCE;                                // block LICM across it/m iterations
      const int irow = it*8 + wid*2 + m;
      const f16* hip_ = hIb + irow*HID;
      f32x16 acc[2] = {};
      // bias kstep
      acc[0] = __builtin_amdgcn_mfma_f32_32x32x16_f16(ab1f[0], bcst, acc[0], 0,0,0);
      acc[1] = __builtin_amdgcn_mfma_f32_32x32x16_f16(ab1f[1], bcst, acc[1], 0,0,0);
      // layer 1: K=288 = 6 octet-steps x {sum, absdiff, prod}
#pragma unroll
      for (int t = 0; t < 6; ++t) {
        MEMFENCE;                              // partition loads: <=6 weight frags live
        f16x8 as0 = *(const f16x8*)(wfr + (((t    )*2+0)*64 + lane)*4);
        f16x8 as1 = *(const f16x8*)(wfr + (((t    )*2+1)*64 + lane)*4);
        f16x8 ad0 = *(const f16x8*)(wfr + (((t+ 6)*2+0)*64 + lane)*4);
        f16x8 ad1_ = *(const f16x8*)(wfr + (((t+ 6)*2+1)*64 + lane)*4);
        f16x8 ap0 = *(const f16x8*)(wfr + (((t+12)*2+0)*64 + lane)*4);
        f16x8 ap1 = *(const f16x8*)(wfr + (((t+12)*2+1)*64 + lane)*4);
        f16x8 hj8 = hjr[t];
        f16x8 hi8 = *(const f16x8*)(hip_ + 16*t + 8*h2);   // wave-uniform broadcast read
        f16x8 su = hi8 + hj8;
        f16x8 di = habs8(hi8 - hj8);
        f16x8 prd = hi8 * hj8;
        __builtin_amdgcn_s_setprio(1);
        acc[0] = __builtin_amdgcn_mfma_f32_32x32x16_f16(as0, su,  acc[0], 0,0,0);
        acc[1] = __builtin_amdgcn_mfma_f32_32x32x16_f16(as1, su,  acc[1], 0,0,0);
        acc[0] = __builtin_amdgcn_mfma_f32_32x32x16_f16(ad0, di,  acc[0], 0,0,0);
        acc[1] = __builtin_amdgcn_mfma_f32_32x32x16_f16(ad1_, di, acc[1], 0,0,0);
        acc[0] = __builtin_amdgcn_mfma_f32_32x32x16_f16(ap0, prd, acc[0], 0,0,0);
        acc[1] = __builtin_amdgcn_mfma_f32_32x32x16_f16(ap1, prd, acc[1], 0,0,0);
        __builtin_amdgcn_s_setprio(0);
      }
      // pack + packed-prelu the 32 z1 values, then permlane-swap h2 halves -> layer-2 B-frags
      u32 w[16];
#pragma unroll
      for (int q = 0; q < 2; ++q)
#pragma unroll
        for (int a = 0; a < 8; ++a) {
          f16x2 pz = pkrtz(acc[q][2*a], acc[q][2*a+1]);
          pz = __builtin_elementwise_max(pz, pz * a1v);
          C2 cv; cv.h = pz; w[q*8 + a] = cv.u;
        }
#pragma unroll
      for (int g = 0; g < 4; ++g) {
        plswap(w[g*4+0], w[g*4+2]);
        plswap(w[g*4+1], w[g*4+3]);
      }
      // layer 2 (swapped): zacc[q2] = W2^T(block q2) @ z1^T, + bias kstep
      f32x16 zacc[2] = {};
      zacc[0] = __builtin_amdgcn_mfma_f32_32x32x16_f16(ab2f[0], bcst, zacc[0], 0,0,0);
      zacc[1] = __builtin_amdgcn_mfma_f32_32x32x16_f16(ab2f[1], bcst, zacc[1], 0,0,0);
#pragma unroll
      for (int t2 = 0; t2 < 4; ++t2) {
        MEMFENCE;                              // keep Wd2 frags per-step (window 2)
        H8 zf; zf.u[0] = w[4*t2]; zf.u[1] = w[4*t2+1]; zf.u[2] = w[4*t2+2]; zf.u[3] = w[4*t2+3];
        f16x8 w20 = *(const f16x8*)(w2a + ((t2*2+0)*64 + lane)*4);
        f16x8 w21 = *(const f16x8*)(w2a + ((t2*2+1)*64 + lane)*4);
        __builtin_amdgcn_s_setprio(1);
        zacc[0] = __builtin_amdgcn_mfma_f32_32x32x16_f16(w20, zf.h, zacc[0], 0,0,0);
        zacc[1] = __builtin_amdgcn_mfma_f32_32x32x16_f16(w21, zf.h, zacc[1], 0,0,0);
        __builtin_amdgcn_s_setprio(0);
      }
      // final: prelu(z2) . W3 — two independent 8-deep fdot2 chains + cross-half add
      float s0 = 0.f, s1 = 0.f;
#pragma unroll
      for (int a = 0; a < 8; ++a) {
        f16x2 pz0 = pkrtz(zacc[0][2*a], zacc[0][2*a+1]);
        pz0 = __builtin_elementwise_max(pz0, pz0 * a2v);
        s0 = fdot2a(pz0, w3q[0][a], s0);
        f16x2 pz1 = pkrtz(zacc[1][2*a], zacc[1][2*a+1]);
        pz1 = __builtin_elementwise_max(pz1, pz1 * a2v);
        s1 = fdot2a(pz1, w3q[1][a], s1);
      }
      float ssum = s0 + s1;
      ssum += __shfl_xor(ssum, 32);
      int gi = I*32 + irow;
      if (h2 == 0 && gi < gj && gj < NN) {
        int eo = bofs + gi*(799 - gi)/2 + (gj - gi - 1);
        out[eo] = ssum + b3;
      }
    }
  }
}

extern "C" void kernel_launch(void* const* d_in, const int* in_sizes, int n_in,
                              void* d_out, int out_size, void* d_ws, size_t ws_size,
                              hipStream_t stream) {
  const float* nf  = (const float*)d_in[1];
  const float* sc  = (const float*)d_in[2];
  const float* sm  = (const float*)d_in[3];
  const float* ss  = (const float*)d_in[4];
  const float* We1 = (const float*)d_in[5];
  const float* be1 = (const float*)d_in[6];
  const float* ae1 = (const float*)d_in[7];
  const float* We2 = (const float*)d_in[8];
  const float* be2 = (const float*)d_in[9];
  const float* ae2 = (const float*)d_in[10];
  const float* W1  = (const float*)d_in[11];
  const float* b1  = (const float*)d_in[12];
  const float* a1  = (const float*)d_in[13];
  const float* W2  = (const float*)d_in[14];
  const float* b2  = (const float*)d_in[15];
  const float* a2  = (const float*)d_in[16];
  const float* W3  = (const float*)d_in[17];
  const float* b3  = (const float*)d_in[18];
  float* out = (float*)d_out;

  char* ws = (char*)d_ws;
  float* mpart = (float*)ws;                             // 256 f32 = 1,024 B
  f16*   hbuf = (f16*)(ws + 1024);                       // 1,228,800 B
  u32*   wq   = (u32*)(ws + 1024 + 1228800);             // 143,360 B

  prep_mean_kernel<<<396, 256, 0, stream>>>(We1, We2, W1, W2, sc, wq, mpart);
  enc_kernel<<<200, 256, 0, stream>>>(sc, nf, sm, ss, be1, ae1, be2, ae2,
                                      mpart, wq, hbuf);
  decoder_kernel<<<BATCH*NPAIRS, 256, 0, stream>>>(hbuf, wq, b1, b2, a1, a2,
                                                   W3, b3, out);
}

// Round 11
// 178.578 us; speedup vs baseline: 1.0292x; 1.0292x over previous
//
#include <hip/hip_runtime.h>

#define NN 400
#define HID 96
#define EDGES 79800
#define BATCH 16
#define ROWS (BATCH*EDGES)
#define NT 13            // node tiles of 32 (tile 12 half-padded)
#define NPAIRS 91        // NT*(NT+1)/2

typedef _Float16 f16;
typedef f16 f16x2 __attribute__((ext_vector_type(2)));
typedef f16 f16x8 __attribute__((ext_vector_type(8)));
typedef __fp16 fp16x2 __attribute__((ext_vector_type(2)));
typedef float f32x16 __attribute__((ext_vector_type(16)));
typedef unsigned int u32;
typedef unsigned long long u64;

union H8 { f16x8 h; u32 u[4]; f16x2 p[4]; fp16x2 q[4]; u64 d[2]; };
union C2 { f16x2 h; fp16x2 q; u32 u; };

__device__ inline f16x2 pkrtz(float a, float b) {
  C2 c; c.q = __builtin_amdgcn_cvt_pkrtz(a, b); return c.h;
}
__device__ inline u32 pkrtz_u(float a, float b) {
  C2 c; c.q = __builtin_amdgcn_cvt_pkrtz(a, b); return c.u;
}
__device__ inline float fdot2a(f16x2 a, f16x2 b, float c) {
#if __has_builtin(__builtin_amdgcn_fdot2)
  C2 ca, cb; ca.h = a; cb.h = b;
  return __builtin_amdgcn_fdot2(ca.q, cb.q, c, false);
#else
  return c + (float)a.x*(float)b.x + (float)a.y*(float)b.y;
#endif
}

__device__ inline f16x8 habs8(f16x8 x) {
  H8 t; t.h = x;
  t.u[0] &= 0x7fff7fffu; t.u[1] &= 0x7fff7fffu;
  t.u[2] &= 0x7fff7fffu; t.u[3] &= 0x7fff7fffu;
  return t.h;
}

__device__ inline f16x8 pack8(float a0,float a1,float a2,float a3,
                              float a4,float a5,float a6,float a7){
  H8 u;
  u.p[0] = pkrtz(a0,a1);
  u.p[1] = pkrtz(a2,a3);
  u.p[2] = pkrtz(a4,a5);
  u.p[3] = pkrtz(a6,a7);
  return u.h;
}

// v_permlane32_swap_b32: vdst.hi32lanes <-> vsrc.lo32lanes.
__device__ inline void plswap(u32 &x, u32 &y) {
  auto r = __builtin_amdgcn_permlane32_swap((int)x, (int)y, false, false);
  x = (u32)r[0]; y = (u32)r[1];
}

// Aliasing fence: stops LICM/scheduler from hoisting+clustering loop-invariant LDS reads
// (the R2-R4 spill source). Register-only ops (MFMA, packs) are unaffected.
#define MEMFENCE asm volatile("" ::: "memory")

// ---------------- fused prep (blocks 0..139) + per-batch partial mean (blocks 140..395) --------
// wq regions (dwords): Wd1 [0,9216)  Wd2 plain-K [9216,11264)  We1 [11264,31232)  We2 [31232,35840)
__global__ void prep_mean_kernel(const float* __restrict__ We1, const float* __restrict__ We2,
                                 const float* __restrict__ W1, const float* __restrict__ W2,
                                 const float* __restrict__ sc,
                                 u32* __restrict__ wq, float* __restrict__ mpart) {
  if (blockIdx.x >= 140) {
    int p = blockIdx.x - 140;           // 0..255
    int b = p >> 4, part = p & 15;
    const float4* src = (const float4*)(sc + (size_t)b*160000) + part*2500;
    float s = 0.f;
    for (int i = threadIdx.x; i < 2500; i += 256) {
      float4 v = src[i];
      s += (v.x + v.y) + (v.z + v.w);
    }
    __shared__ float red[256];
    red[threadIdx.x] = s; __syncthreads();
    for (int off = 128; off > 0; off >>= 1) {
      if (threadIdx.x < off) red[threadIdx.x] += red[threadIdx.x + off];
      __syncthreads();
    }
    if (threadIdx.x == 0) mpart[p] = red[0];
    return;
  }
  int D = blockIdx.x*256 + threadIdx.x;     // 0..35839
  float v0, v1;
  if (D < 9216) {               // W_d1 frags (288 x 64), d = 32q+c  (A-frag == B-frag layout)
    int frag = D >> 8;  int t = frag >> 1, q = frag & 1;
    int rem = D & 255;  int lane = rem >> 2, dj = rem & 3;
    int c = lane & 31, h2 = lane >> 5;
    int k = 16*t + 8*h2 + 2*dj;
    int d = 32*q + c;
    v0 = W1[k*64 + d]; v1 = W1[(k+1)*64 + d];
  } else if (D < 11264) {       // W_d2 frags, PLAIN K (A-frags for swapped layer-2)
    int Dl = D - 9216;
    int frag = Dl >> 8; int t2 = frag >> 1, q = frag & 1;
    int rem = Dl & 255; int lane = rem >> 2, dj = rem & 3;
    int c = lane & 31, h2 = lane >> 5;
    int k = 16*t2 + 8*h2 + 2*dj;
    int d = 32*q + c;
    v0 = W2[k*64 + d]; v1 = W2[(k+1)*64 + d];
  } else if (D < 31232) {       // W_e1 frags (416 x 96), sc features first, static at 400
    int Dl = D - 11264;
    int frag = Dl >> 8; int t = frag/3, ct = frag - 3*t;
    int rem = Dl & 255; int lane = rem >> 2, dj = rem & 3;
    int c = lane & 31, h2 = lane >> 5;
    int k0 = 16*t + 8*h2 + 2*dj, k1 = k0 + 1;
    int d = 32*ct + c;
    v0 = (k0 < 400) ? We1[(8+k0)*96 + d] : (k0 < 408 ? We1[(k0-400)*96 + d] : 0.f);
    v1 = (k1 < 400) ? We1[(8+k1)*96 + d] : (k1 < 408 ? We1[(k1-400)*96 + d] : 0.f);
  } else {                      // W_e2 frags (96 x 96), plain K order
    int Dl = D - 31232;
    int frag = Dl >> 8; int t = frag/3, ct = frag - 3*t;
    int rem = Dl & 255; int lane = rem >> 2, dj = rem & 3;
    int c = lane & 31, h2 = lane >> 5;
    int k = 16*t + 8*h2 + 2*dj;
    int d = 32*ct + c;
    v0 = We2[k*96 + d]; v1 = We2[(k+1)*96 + d];
  }
  wq[D] = pkrtz_u(v0, v1);
}

// ---------------- encoder v2: per-wave full-K, 2 barriers, zero combine (R9, kept) ------------
__global__ __launch_bounds__(256) void enc_kernel(
    const float* __restrict__ sc, const float* __restrict__ nf,
    const float* __restrict__ smean, const float* __restrict__ sstd,
    const float* __restrict__ be1, const float* __restrict__ ae1,
    const float* __restrict__ be2, const float* __restrict__ ae2,
    const float* __restrict__ mpart, const u32* __restrict__ wq,
    f16* __restrict__ hout) {
  __shared__ u32 lds[6720 + 1600];
  const int tid = threadIdx.x;
  const int wid = tid >> 6, lane = tid & 63;
  const int c = lane & 31, h2 = lane >> 5;
  const int r0 = blockIdx.x * 32;
  // Phase A: stage normalized sc rows as f16 (all waves)
  {
    int row = tid >> 3, seg = tid & 7;
    int r = r0 + row;
    int b = r / 400;
    float ms = 0.f;
    const float4* mp4 = (const float4*)(mpart + 16*b);
#pragma unroll
    for (int k = 0; k < 4; ++k) { float4 v = mp4[k]; ms += (v.x+v.y)+(v.z+v.w); }
    float rm = 1.f / fmaxf(ms*(1.f/160000.f), 1e-8f);
    const float4* src = (const float4*)(sc + (size_t)r*400);
#pragma unroll
    for (int i = 0; i < 13; ++i) {
      int col4 = seg + 8*i;
      if (col4 < 100) {
        float4 v = src[col4];
        u32 lo = pkrtz_u(v.x*rm, v.y*rm);
        u32 hi = pkrtz_u(v.z*rm, v.w*rm);
        *(u64*)(lds + row*210 + col4*2) = (u64)lo | ((u64)hi << 32);
      }
    }
  }
  // weight preload (per-wave ct) + static-feature frag: independent of LDS staging,
  // issued before the barrier so the global latency hides under staging.
  f16x8 bfr[26], we2r[6], af25;
  if (wid < 3) {
    const u32* wb1 = wq + 11264;
#pragma unroll
    for (int t = 0; t < 26; ++t)
      bfr[t] = *(const f16x8*)(wb1 + ((t*3+wid)*64 + lane)*4);
    const u32* wb2 = wq + 31232;
#pragma unroll
    for (int t = 0; t < 6; ++t)
      we2r[t] = *(const f16x8*)(wb2 + ((t*3+wid)*64 + lane)*4);
    af25 = (f16x8){};
    if (h2 == 0) {
      int r = r0 + c;
      float q0[8];
#pragma unroll
      for (int j = 0; j < 8; ++j)
        q0[j] = (nf[r*8 + j] - smean[j]) / (sstd[j] + 1e-8f);
      af25 = pack8(q0[0],q0[1],q0[2],q0[3],q0[4],q0[5],q0[6],q0[7]);
    }
  }
  __syncthreads();
  f16* zb16 = (f16*)(lds + 6720);
  if (wid < 3) {
    const float a1 = *ae1;
    float bv = be1[32*wid + c];
    f32x16 acc;
#pragma unroll
    for (int i = 0; i < 16; ++i) acc[i] = bv;
#pragma unroll
    for (int t = 0; t < 25; ++t) {
      H8 av;
      const u32* ap = lds + c*210 + 8*t + 4*h2;
      av.d[0] = *(const u64*)ap;
      av.d[1] = *(const u64*)(ap + 2);
      acc = __builtin_amdgcn_mfma_f32_32x32x16_f16(av.h, bfr[t], acc, 0,0,0);
    }
    acc = __builtin_amdgcn_mfma_f32_32x32x16_f16(af25, bfr[25], acc, 0,0,0);
#pragma unroll
    for (int r = 0; r < 16; ++r) {
      float v = acc[r]; v = fmaxf(v, a1*v);
      int row = (r & 3) + 8*(r >> 2) + 4*h2;
      zb16[row*100 + 32*wid + c] = (f16)v;
    }
  }
  __syncthreads();
  if (wid < 3) {
    const float a2 = *ae2;
    float bv = be2[32*wid + c];
    f32x16 acc2;
#pragma unroll
    for (int i = 0; i < 16; ++i) acc2[i] = bv;
#pragma unroll
    for (int t = 0; t < 6; ++t) {
      f16x8 af = *(const f16x8*)(zb16 + c*100 + 16*t + 8*h2);
      acc2 = __builtin_amdgcn_mfma_f32_32x32x16_f16(af, we2r[t], acc2, 0,0,0);
    }
#pragma unroll
    for (int rr = 0; rr < 16; ++rr) {
      int row = (rr & 3) + 8*(rr >> 2) + 4*h2;
      float v = acc2[rr]; v = fmaxf(v, a2*v);
      hout[(r0 + row)*96 + 32*wid + c] = (f16)v;
    }
  }
}

// ---------------- decoder v10: m-PAIRED + fences at 3 blocks/CU, bias/W3 de-registered --------
// R10 lesson: m-seq at 3 blocks = no gain (doubled weight ds_reads ate the TLP win). Winning
// combo = m-paired (224 b128/wave) + 3 waves/SIMD + no spill. To fit the (256,3) ~168-reg cap:
//  (1) bias MFMAs deleted; acc/zacc init directly from f32 bias staged in LDS (BIT-EXACT:
//      the bias MFMA added b[d]*1.0 in f32 as the starting value) — frees 40 regs, -8% MFMA;
//  (2) packed-W3 table moved to LDS (32 u32, broadcast reads) — frees 16 regs.
// Peak ~152 regs <= 168. LDS 51,840 B x 3 = 155,520 <= 163,840.
__global__ __launch_bounds__(256, 3) void decoder_kernel(
    const f16* __restrict__ hbuf, const u32* __restrict__ wq,
    const float* __restrict__ b1, const float* __restrict__ b2,
    const float* __restrict__ ad1, const float* __restrict__ ad2,
    const float* __restrict__ W3, const float* __restrict__ b3p,
    float* __restrict__ out) {
  __shared__ alignas(16) u32 smem[12960];
  const int tid = threadIdx.x;
  // task decode
  int p = blockIdx.x;
  int b = p / NPAIRS, pr = p - b*NPAIRS;
  int I = 0;
  while (pr >= NT - I) { pr -= NT - I; ++I; }
  const int J = I + pr;
  // stage hI rows: 32 rows x 48 dwords (clamped for tile 12)
  for (int i = tid; i < 384; i += 256) {
    int row = i / 12, off = i - row*12;
    int nb = I*32 + row; nb = nb < NN ? nb : NN-1;
    const float4* src = (const float4*)(hbuf + (size_t)(b*NN + nb)*HID) + off;
    *((float4*)(smem + row*48) + off) = *src;
  }
  // stage Wd1 (9216 dw) + Wd2 (2048 dw) contiguously
  {
    float4* dst = (float4*)(smem + 1536);
    const float4* srcw = (const float4*)wq;
    for (int i = tid; i < 2816; i += 256) dst[i] = srcw[i];
  }
  // stage biases (f32) + packed W3 table
  if (tid < 64) {
    ((float*)(smem + 12800))[tid] = b1[tid];
    ((float*)(smem + 12864))[tid] = b2[tid];
  }
  if (tid < 32) {
    int hh = tid >> 4, rem = tid & 15, q2 = rem >> 3, a = rem & 7;
    int base = 32*q2 + 8*(a >> 1) + 2*(a & 1) + 4*hh;
    smem[12928 + tid] = pkrtz_u(W3[base], W3[base + 1]);
  }

  const int lane = tid & 63;
  const int wid  = tid >> 6;
  const int c = lane & 31, h2 = lane >> 5;
  const int gj = J*32 + c;
  const int gjc = gj < NN ? gj : NN-1;
  // hj frags for this lane's edge column, loop-invariant -> registers (from global, L2-hot)
  f16x8 hjr[6];
  {
    const f16* hjp = hbuf + (size_t)(b*NN + gjc)*HID + 8*h2;
#pragma unroll
    for (int t = 0; t < 6; ++t) hjr[t] = *(const f16x8*)(hjp + 16*t);
  }
  const float a1 = *ad1, a2 = *ad2, b3 = *b3p;
  const f16x2 a1v = pkrtz(a1, a1);
  const f16x2 a2v = pkrtz(a2, a2);
  __syncthreads();

  const f16* hIb = (const f16*)smem;
  const u32* wfr = smem + 1536;
  const u32* w2a = smem + 10752;
  const float* b1f = (const float*)(smem + 12800);
  const float* b2f = (const float*)(smem + 12864);
  const u32* w3l = smem + 12928;
  const int bofs = b*EDGES;

#pragma unroll 1
  for (int it = 0; it < 4; ++it) {
    MEMFENCE;                                  // block LICM across the it-loop
    const int i0 = it*8 + wid*2;
    const f16* hi0 = hIb + (i0+0)*HID;
    const f16* hi1 = hIb + (i0+1)*HID;
    // acc init = f32 bias from LDS (replaces bias MFMAs; bit-exact)
    f32x16 acc[2][2];
#pragma unroll
    for (int q = 0; q < 2; ++q)
#pragma unroll
      for (int a = 0; a < 8; ++a) {
        int base = 32*q + 8*(a >> 1) + 2*(a & 1) + 4*h2;
        float2 bv = *(const float2*)(b1f + base);
        acc[0][q][2*a] = bv.x; acc[0][q][2*a+1] = bv.y;
        acc[1][q][2*a] = bv.x; acc[1][q][2*a+1] = bv.y;
      }
    // layer 1: K=288 = 6 octet-steps x {sum, absdiff, prod}; A = W1^T frags from LDS
#pragma unroll
    for (int t = 0; t < 6; ++t) {
      MEMFENCE;                                // partition loads: <=6 weight frags live
      f16x8 as0 = *(const f16x8*)(wfr + (((t    )*2+0)*64 + lane)*4);
      f16x8 as1 = *(const f16x8*)(wfr + (((t    )*2+1)*64 + lane)*4);
      f16x8 ad0 = *(const f16x8*)(wfr + (((t+ 6)*2+0)*64 + lane)*4);
      f16x8 ad1_ = *(const f16x8*)(wfr + (((t+ 6)*2+1)*64 + lane)*4);
      f16x8 ap0 = *(const f16x8*)(wfr + (((t+12)*2+0)*64 + lane)*4);
      f16x8 ap1 = *(const f16x8*)(wfr + (((t+12)*2+1)*64 + lane)*4);
      f16x8 hj8 = hjr[t];
#pragma unroll
      for (int m = 0; m < 2; ++m) {
        f16x8 hi8 = *(const f16x8*)((m ? hi1 : hi0) + 16*t + 8*h2);   // broadcast read
        f16x8 su = hi8 + hj8;
        f16x8 di = habs8(hi8 - hj8);
        f16x8 prd = hi8 * hj8;
        __builtin_amdgcn_s_setprio(1);
        acc[m][0] = __builtin_amdgcn_mfma_f32_32x32x16_f16(as0, su,  acc[m][0], 0,0,0);
        acc[m][1] = __builtin_amdgcn_mfma_f32_32x32x16_f16(as1, su,  acc[m][1], 0,0,0);
        acc[m][0] = __builtin_amdgcn_mfma_f32_32x32x16_f16(ad0, di,  acc[m][0], 0,0,0);
        acc[m][1] = __builtin_amdgcn_mfma_f32_32x32x16_f16(ad1_, di, acc[m][1], 0,0,0);
        acc[m][0] = __builtin_amdgcn_mfma_f32_32x32x16_f16(ap0, prd, acc[m][0], 0,0,0);
        acc[m][1] = __builtin_amdgcn_mfma_f32_32x32x16_f16(ap1, prd, acc[m][1], 0,0,0);
        __builtin_amdgcn_s_setprio(0);
      }
    }
#pragma unroll
    for (int m = 0; m < 2; ++m) {
      MEMFENCE;
      // pack + packed-prelu the 32 z1 values, then permlane-swap h2 halves -> layer-2 B-frags
      u32 w[16];
#pragma unroll
      for (int q = 0; q < 2; ++q)
#pragma unroll
        for (int a = 0; a < 8; ++a) {
          f16x2 pz = pkrtz(acc[m][q][2*a], acc[m][q][2*a+1]);
          pz = __builtin_elementwise_max(pz, pz * a1v);
          C2 cv; cv.h = pz; w[q*8 + a] = cv.u;
        }
#pragma unroll
      for (int g = 0; g < 4; ++g) {
        plswap(w[g*4+0], w[g*4+2]);
        plswap(w[g*4+1], w[g*4+3]);
      }
      // layer 2 (swapped): zacc init = f32 bias from LDS, then 8 MFMAs
      f32x16 zacc[2];
#pragma unroll
      for (int q = 0; q < 2; ++q)
#pragma unroll
        for (int a = 0; a < 8; ++a) {
          int base = 32*q + 8*(a >> 1) + 2*(a & 1) + 4*h2;
          float2 bv = *(const float2*)(b2f + base);
          zacc[q][2*a] = bv.x; zacc[q][2*a+1] = bv.y;
        }
#pragma unroll
      for (int t2 = 0; t2 < 4; ++t2) {
        MEMFENCE;                              // keep Wd2 frags per-step (window 2)
        H8 zf; zf.u[0] = w[4*t2]; zf.u[1] = w[4*t2+1]; zf.u[2] = w[4*t2+2]; zf.u[3] = w[4*t2+3];
        f16x8 w20 = *(const f16x8*)(w2a + ((t2*2+0)*64 + lane)*4);
        f16x8 w21 = *(const f16x8*)(w2a + ((t2*2+1)*64 + lane)*4);
        __builtin_amdgcn_s_setprio(1);
        zacc[0] = __builtin_amdgcn_mfma_f32_32x32x16_f16(w20, zf.h, zacc[0], 0,0,0);
        zacc[1] = __builtin_amdgcn_mfma_f32_32x32x16_f16(w21, zf.h, zacc[1], 0,0,0);
        __builtin_amdgcn_s_setprio(0);
      }
      // final: prelu(z2) . W3 (packed pairs from LDS, broadcast) — two 8-deep fdot2 chains
      float s0 = 0.f, s1 = 0.f;
#pragma unroll
      for (int a = 0; a < 8; ++a) {
        C2 wv0; wv0.u = w3l[(h2 << 4) | a];
        f16x2 pz0 = pkrtz(zacc[0][2*a], zacc[0][2*a+1]);
        pz0 = __builtin_elementwise_max(pz0, pz0 * a2v);
        s0 = fdot2a(pz0, wv0.h, s0);
        C2 wv1; wv1.u = w3l[(h2 << 4) | 8 | a];
        f16x2 pz1 = pkrtz(zacc[1][2*a], zacc[1][2*a+1]);
        pz1 = __builtin_elementwise_max(pz1, pz1 * a2v);
        s1 = fdot2a(pz1, wv1.h, s1);
      }
      float ssum = s0 + s1;
      ssum += __shfl_xor(ssum, 32);
      int gi = I*32 + i0 + m;
      if (h2 == 0 && gi < gj && gj < NN) {
        int eo = bofs + gi*(799 - gi)/2 + (gj - gi - 1);
        out[eo] = ssum + b3;
      }
    }
  }
}

extern "C" void kernel_launch(void* const* d_in, const int* in_sizes, int n_in,
                              void* d_out, int out_size, void* d_ws, size_t ws_size,
                              hipStream_t stream) {
  const float* nf  = (const float*)d_in[1];
  const float* sc  = (const float*)d_in[2];
  const float* sm  = (const float*)d_in[3];
  const float* ss  = (const float*)d_in[4];
  const float* We1 = (const float*)d_in[5];
  const float* be1 = (const float*)d_in[6];
  const float* ae1 = (const float*)d_in[7];
  const float* We2 = (const float*)d_in[8];
  const float* be2 = (const float*)d_in[9];
  const float* ae2 = (const float*)d_in[10];
  const float* W1  = (const float*)d_in[11];
  const float* b1  = (const float*)d_in[12];
  const float* a1  = (const float*)d_in[13];
  const float* W2  = (const float*)d_in[14];
  const float* b2  = (const float*)d_in[15];
  const float* a2  = (const float*)d_in[16];
  const float* W3  = (const float*)d_in[17];
  const float* b3  = (const float*)d_in[18];
  float* out = (float*)d_out;

  char* ws = (char*)d_ws;
  float* mpart = (float*)ws;                             // 256 f32 = 1,024 B
  f16*   hbuf = (f16*)(ws + 1024);                       // 1,228,800 B
  u32*   wq   = (u32*)(ws + 1024 + 1228800);             // 143,360 B

  prep_mean_kernel<<<396, 256, 0, stream>>>(We1, We2, W1, W2, sc, wq, mpart);
  enc_kernel<<<200, 256, 0, stream>>>(sc, nf, sm, ss, be1, ae1, be2, ae2,
                                      mpart, wq, hbuf);
  decoder_kernel<<<BATCH*NPAIRS, 256, 0, stream>>>(hbuf, wq, b1, b2, a1, a2,
                                                   W3, b3, out);
}

// Round 12
// 170.028 us; speedup vs baseline: 1.0810x; 1.0503x over previous
//
#include <hip/hip_runtime.h>

#define NN 400
#define HID 96
#define EDGES 79800
#define BATCH 16
#define ROWS (BATCH*EDGES)
#define NT 13            // node tiles of 32 (tile 12 half-padded)
#define NPAIRS 91        // NT*(NT+1)/2

typedef _Float16 f16;
typedef f16 f16x2 __attribute__((ext_vector_type(2)));
typedef f16 f16x8 __attribute__((ext_vector_type(8)));
typedef __fp16 fp16x2 __attribute__((ext_vector_type(2)));
typedef float f32x16 __attribute__((ext_vector_type(16)));
typedef unsigned int u32;
typedef unsigned long long u64;

union H8 { f16x8 h; u32 u[4]; f16x2 p[4]; fp16x2 q[4]; u64 d[2]; };
union C2 { f16x2 h; fp16x2 q; u32 u; };

__device__ inline f16x2 pkrtz(float a, float b) {
  C2 c; c.q = __builtin_amdgcn_cvt_pkrtz(a, b); return c.h;
}
__device__ inline u32 pkrtz_u(float a, float b) {
  C2 c; c.q = __builtin_amdgcn_cvt_pkrtz(a, b); return c.u;
}
__device__ inline float fdot2a(f16x2 a, f16x2 b, float c) {
#if __has_builtin(__builtin_amdgcn_fdot2)
  C2 ca, cb; ca.h = a; cb.h = b;
  return __builtin_amdgcn_fdot2(ca.q, cb.q, c, false);
#else
  return c + (float)a.x*(float)b.x + (float)a.y*(float)b.y;
#endif
}

__device__ inline f16x8 habs8(f16x8 x) {
  H8 t; t.h = x;
  t.u[0] &= 0x7fff7fffu; t.u[1] &= 0x7fff7fffu;
  t.u[2] &= 0x7fff7fffu; t.u[3] &= 0x7fff7fffu;
  return t.h;
}

__device__ inline f16x8 pack8(float a0,float a1,float a2,float a3,
                              float a4,float a5,float a6,float a7){
  H8 u;
  u.p[0] = pkrtz(a0,a1);
  u.p[1] = pkrtz(a2,a3);
  u.p[2] = pkrtz(a4,a5);
  u.p[3] = pkrtz(a6,a7);
  return u.h;
}

// v_permlane32_swap_b32: vdst.hi32lanes <-> vsrc.lo32lanes.
__device__ inline void plswap(u32 &x, u32 &y) {
  auto r = __builtin_amdgcn_permlane32_swap((int)x, (int)y, false, false);
  x = (u32)r[0]; y = (u32)r[1];
}

// Aliasing fence: stops LICM/scheduler from hoisting+clustering loop-invariant LDS reads
// (the R2-R4 spill source). Register-only ops (MFMA, packs) are unaffected.
#define MEMFENCE asm volatile("" ::: "memory")

// ---------------- fused prep (blocks 0..139) + per-batch partial mean (blocks 140..395) --------
// wq regions (dwords): Wd1 [0,9216)  Wd2 plain-K [9216,11264)  We1 [11264,31232)  We2 [31232,35840)
// Wd1 frags: f = t*2+q, t=0..5 sum (k 0..95), t=6..11 diff, t=12..17 prod.
__global__ void prep_mean_kernel(const float* __restrict__ We1, const float* __restrict__ We2,
                                 const float* __restrict__ W1, const float* __restrict__ W2,
                                 const float* __restrict__ sc,
                                 u32* __restrict__ wq, float* __restrict__ mpart) {
  if (blockIdx.x >= 140) {
    int p = blockIdx.x - 140;           // 0..255
    int b = p >> 4, part = p & 15;
    const float4* src = (const float4*)(sc + (size_t)b*160000) + part*2500;
    float s = 0.f;
    for (int i = threadIdx.x; i < 2500; i += 256) {
      float4 v = src[i];
      s += (v.x + v.y) + (v.z + v.w);
    }
    __shared__ float red[256];
    red[threadIdx.x] = s; __syncthreads();
    for (int off = 128; off > 0; off >>= 1) {
      if (threadIdx.x < off) red[threadIdx.x] += red[threadIdx.x + off];
      __syncthreads();
    }
    if (threadIdx.x == 0) mpart[p] = red[0];
    return;
  }
  int D = blockIdx.x*256 + threadIdx.x;     // 0..35839
  float v0, v1;
  if (D < 9216) {               // W_d1 frags (288 x 64), d = 32q+c  (A-frag == B-frag layout)
    int frag = D >> 8;  int t = frag >> 1, q = frag & 1;
    int rem = D & 255;  int lane = rem >> 2, dj = rem & 3;
    int c = lane & 31, h2 = lane >> 5;
    int k = 16*t + 8*h2 + 2*dj;
    int d = 32*q + c;
    v0 = W1[k*64 + d]; v1 = W1[(k+1)*64 + d];
  } else if (D < 11264) {       // W_d2 frags, PLAIN K (A-frags for swapped layer-2)
    int Dl = D - 9216;
    int frag = Dl >> 8; int t2 = frag >> 1, q = frag & 1;
    int rem = Dl & 255; int lane = rem >> 2, dj = rem & 3;
    int c = lane & 31, h2 = lane >> 5;
    int k = 16*t2 + 8*h2 + 2*dj;
    int d = 32*q + c;
    v0 = W2[k*64 + d]; v1 = W2[(k+1)*64 + d];
  } else if (D < 31232) {       // W_e1 frags (416 x 96), sc features first, static at 400
    int Dl = D - 11264;
    int frag = Dl >> 8; int t = frag/3, ct = frag - 3*t;
    int rem = Dl & 255; int lane = rem >> 2, dj = rem & 3;
    int c = lane & 31, h2 = lane >> 5;
    int k0 = 16*t + 8*h2 + 2*dj, k1 = k0 + 1;
    int d = 32*ct + c;
    v0 = (k0 < 400) ? We1[(8+k0)*96 + d] : (k0 < 408 ? We1[(k0-400)*96 + d] : 0.f);
    v1 = (k1 < 400) ? We1[(8+k1)*96 + d] : (k1 < 408 ? We1[(k1-400)*96 + d] : 0.f);
  } else {                      // W_e2 frags (96 x 96), plain K order
    int Dl = D - 31232;
    int frag = Dl >> 8; int t = frag/3, ct = frag - 3*t;
    int rem = Dl & 255; int lane = rem >> 2, dj = rem & 3;
    int c = lane & 31, h2 = lane >> 5;
    int k = 16*t + 8*h2 + 2*dj;
    int d = 32*ct + c;
    v0 = We2[k*96 + d]; v1 = We2[(k+1)*96 + d];
  }
  wq[D] = pkrtz_u(v0, v1);
}

// ---------------- encoder v3: R9 form + fused u = h @ Ws per-node precompute ----------------
// u-phase (new): after layer 2, stage h (post-prelu) into LDS, barrier, then waves 0/1 compute
// u^T = Ws^T @ h^T (q = wid block of d1): C[d1][node] — lane c = node, regs = d1-slots.
// Stored as ubuf[node][h2*32 + q*16 + r] — exactly the per-lane layout the decoder consumes.
// LDS (dwords): staging 6720, zb16 1600, h_lds 1600 -> 39,680 B.
__global__ __launch_bounds__(256) void enc_kernel(
    const float* __restrict__ sc, const float* __restrict__ nf,
    const float* __restrict__ smean, const float* __restrict__ sstd,
    const float* __restrict__ be1, const float* __restrict__ ae1,
    const float* __restrict__ be2, const float* __restrict__ ae2,
    const float* __restrict__ mpart, const u32* __restrict__ wq,
    f16* __restrict__ hout, float* __restrict__ ubuf) {
  __shared__ u32 lds[6720 + 1600 + 1600];
  const int tid = threadIdx.x;
  const int wid = tid >> 6, lane = tid & 63;
  const int c = lane & 31, h2 = lane >> 5;
  const int r0 = blockIdx.x * 32;
  // Phase A: stage normalized sc rows as f16 (all waves)
  {
    int row = tid >> 3, seg = tid & 7;
    int r = r0 + row;
    int b = r / 400;
    float ms = 0.f;
    const float4* mp4 = (const float4*)(mpart + 16*b);
#pragma unroll
    for (int k = 0; k < 4; ++k) { float4 v = mp4[k]; ms += (v.x+v.y)+(v.z+v.w); }
    float rm = 1.f / fmaxf(ms*(1.f/160000.f), 1e-8f);
    const float4* src = (const float4*)(sc + (size_t)r*400);
#pragma unroll
    for (int i = 0; i < 13; ++i) {
      int col4 = seg + 8*i;
      if (col4 < 100) {
        float4 v = src[col4];
        u32 lo = pkrtz_u(v.x*rm, v.y*rm);
        u32 hi = pkrtz_u(v.z*rm, v.w*rm);
        *(u64*)(lds + row*210 + col4*2) = (u64)lo | ((u64)hi << 32);
      }
    }
  }
  // weight preload (per-wave ct) + Ws frags (u-phase) + static-feature frag
  f16x8 bfr[26], we2r[6], af25, wsf[6];
  if (wid < 3) {
    const u32* wb1 = wq + 11264;
#pragma unroll
    for (int t = 0; t < 26; ++t)
      bfr[t] = *(const f16x8*)(wb1 + ((t*3+wid)*64 + lane)*4);
    const u32* wb2 = wq + 31232;
#pragma unroll
    for (int t = 0; t < 6; ++t)
      we2r[t] = *(const f16x8*)(wb2 + ((t*3+wid)*64 + lane)*4);
    af25 = (f16x8){};
    if (h2 == 0) {
      int r = r0 + c;
      float q0[8];
#pragma unroll
      for (int j = 0; j < 8; ++j)
        q0[j] = (nf[r*8 + j] - smean[j]) / (sstd[j] + 1e-8f);
      af25 = pack8(q0[0],q0[1],q0[2],q0[3],q0[4],q0[5],q0[6],q0[7]);
    }
  }
  if (wid < 2) {
#pragma unroll
    for (int t = 0; t < 6; ++t)
      wsf[t] = *(const f16x8*)(wq + ((t*2+wid)*64 + lane)*4);
  }
  __syncthreads();
  f16* zb16 = (f16*)(lds + 6720);
  if (wid < 3) {
    const float a1 = *ae1;
    float bv = be1[32*wid + c];
    f32x16 acc;
#pragma unroll
    for (int i = 0; i < 16; ++i) acc[i] = bv;
#pragma unroll
    for (int t = 0; t < 25; ++t) {
      H8 av;
      const u32* ap = lds + c*210 + 8*t + 4*h2;
      av.d[0] = *(const u64*)ap;
      av.d[1] = *(const u64*)(ap + 2);
      acc = __builtin_amdgcn_mfma_f32_32x32x16_f16(av.h, bfr[t], acc, 0,0,0);
    }
    acc = __builtin_amdgcn_mfma_f32_32x32x16_f16(af25, bfr[25], acc, 0,0,0);
#pragma unroll
    for (int r = 0; r < 16; ++r) {
      float v = acc[r]; v = fmaxf(v, a1*v);
      int row = (r & 3) + 8*(r >> 2) + 4*h2;
      zb16[row*100 + 32*wid + c] = (f16)v;
    }
  }
  __syncthreads();
  f16* hl = (f16*)(lds + 6720 + 1600);
  if (wid < 3) {
    const float a2 = *ae2;
    float bv = be2[32*wid + c];
    f32x16 acc2;
#pragma unroll
    for (int i = 0; i < 16; ++i) acc2[i] = bv;
#pragma unroll
    for (int t = 0; t < 6; ++t) {
      f16x8 af = *(const f16x8*)(zb16 + c*100 + 16*t + 8*h2);
      acc2 = __builtin_amdgcn_mfma_f32_32x32x16_f16(af, we2r[t], acc2, 0,0,0);
    }
#pragma unroll
    for (int rr = 0; rr < 16; ++rr) {
      int row = (rr & 3) + 8*(rr >> 2) + 4*h2;
      float v = acc2[rr]; v = fmaxf(v, a2*v);
      f16 hv = (f16)v;
      hout[(r0 + row)*96 + 32*wid + c] = hv;
      hl[row*100 + 32*wid + c] = hv;
    }
  }
  __syncthreads();
  // u-phase: u^T = Ws^T @ h^T, wave wid = q-block
  if (wid < 2) {
    f32x16 au = {};
#pragma unroll
    for (int t = 0; t < 6; ++t) {
      f16x8 hf = *(const f16x8*)(hl + c*100 + 16*t + 8*h2);
      au = __builtin_amdgcn_mfma_f32_32x32x16_f16(wsf[t], hf, au, 0,0,0);
    }
    float* up = ubuf + (size_t)(r0 + c)*64 + h2*32 + wid*16;
    union { f32x16 v; float4 f[4]; } uu; uu.v = au;
#pragma unroll
    for (int i4 = 0; i4 < 4; ++i4)
      *(float4*)(up + 4*i4) = uu.f[i4];
  }
}

// ---------------- decoder v11: sum-factorized layer 1 (u_i + u_j precomputed) -----------------
// z1 = u_i + u_j + |hi-hj|@Wd + (hi*hj)@Wp + b1 — sum-term MFMAs deleted (352->256 MFMA/wave,
// -27%), su VALU gone, Wd1 staging 36->24 frags. u_J: 32 regs/lane (loop-invariant, lane c =
// edge col gj). u_I: LDS broadcast per i-row. m-paired, 3 blocks/CU, fences (R11 base).
// LDS (dwords): hI [0,1536) Wd+Wp [1536,7680) Wd2 [7680,9728) b1 [9728,9792) b2 [9792,9856)
//               w3 [9856,9888) uI [9888,11936) = 47,744 B x 3 = 143,232 <= 163,840.
__global__ __launch_bounds__(256, 3) void decoder_kernel(
    const f16* __restrict__ hbuf, const u32* __restrict__ wq,
    const float* __restrict__ b1, const float* __restrict__ b2,
    const float* __restrict__ ad1, const float* __restrict__ ad2,
    const float* __restrict__ W3, const float* __restrict__ b3p,
    const float* __restrict__ ubuf, float* __restrict__ out) {
  __shared__ alignas(16) u32 smem[11936];
  const int tid = threadIdx.x;
  // task decode
  int p = blockIdx.x;
  int b = p / NPAIRS, pr = p - b*NPAIRS;
  int I = 0;
  while (pr >= NT - I) { pr -= NT - I; ++I; }
  const int J = I + pr;
  // stage hI rows: 32 rows x 48 dwords (clamped for tile 12)
  for (int i = tid; i < 384; i += 256) {
    int row = i / 12, off = i - row*12;
    int nb = I*32 + row; nb = nb < NN ? nb : NN-1;
    const float4* src = (const float4*)(hbuf + (size_t)(b*NN + nb)*HID) + off;
    *((float4*)(smem + row*48) + off) = *src;
  }
  // stage Wd1 diff+prod (frags 12..35 = dwords 3072..9216) + Wd2 (9216..11264): 8192 dw
  {
    float4* dst = (float4*)(smem + 1536);
    const float4* srcw = (const float4*)wq + 768;
    for (int i = tid; i < 2048; i += 256) dst[i] = srcw[i];
  }
  // stage u_I tile: 32 rows x 64 f32 (clamped)
  {
    const float4* us = (const float4*)(ubuf + (size_t)(b*NN)*64);
    float4* ud = (float4*)(smem + 9888);
    for (int i = tid; i < 512; i += 256) {
      int row = i >> 4, off = i & 15;
      int nb = I*32 + row; nb = nb < NN ? nb : NN-1;
      ud[row*16 + off] = us[nb*16 + off];
    }
  }
  // stage biases (f32) + packed W3 table
  if (tid < 64) {
    ((float*)(smem + 9728))[tid] = b1[tid];
    ((float*)(smem + 9792))[tid] = b2[tid];
  }
  if (tid < 32) {
    int hh = tid >> 4, rem = tid & 15, q2 = rem >> 3, a = rem & 7;
    int base = 32*q2 + 8*(a >> 1) + 2*(a & 1) + 4*hh;
    smem[9856 + tid] = pkrtz_u(W3[base], W3[base + 1]);
  }

  const int lane = tid & 63;
  const int wid  = tid >> 6;
  const int c = lane & 31, h2 = lane >> 5;
  const int gj = J*32 + c;
  const int gjc = gj < NN ? gj : NN-1;
  // hj frags (diff/prod inputs) + u_j (loop-invariant per lane)
  f16x8 hjr[6];
  {
    const f16* hjp = hbuf + (size_t)(b*NN + gjc)*HID + 8*h2;
#pragma unroll
    for (int t = 0; t < 6; ++t) hjr[t] = *(const f16x8*)(hjp + 16*t);
  }
  union { float4 f4[8]; float s[32]; } u_j;
  {
    const float4* ujp = (const float4*)(ubuf + (size_t)(b*NN + gjc)*64 + h2*32);
#pragma unroll
    for (int i4 = 0; i4 < 8; ++i4) u_j.f4[i4] = ujp[i4];
  }
  const float a1 = *ad1, a2 = *ad2, b3 = *b3p;
  const f16x2 a1v = pkrtz(a1, a1);
  const f16x2 a2v = pkrtz(a2, a2);
  __syncthreads();

  const f16* hIb = (const f16*)smem;
  const u32* wfr = smem + 1536;
  const u32* w2a = smem + 7680;
  const float* b1f = (const float*)(smem + 9728);
  const float* b2f = (const float*)(smem + 9792);
  const u32* w3l = smem + 9856;
  const float* uIf = (const float*)(smem + 9888);
  const int bofs = b*EDGES;

#pragma unroll 1
  for (int it = 0; it < 4; ++it) {
    MEMFENCE;                                  // block LICM across the it-loop
    const int i0 = it*8 + wid*2;
    const f16* hi0 = hIb + (i0+0)*HID;
    const f16* hi1 = hIb + (i0+1)*HID;
    // acc init = b1 + u_i + u_j (replaces bias+sum MFMAs)
    const float* uI0 = uIf + (i0+0)*64 + h2*32;
    const float* uI1 = uIf + (i0+1)*64 + h2*32;
    f32x16 acc[2][2];
#pragma unroll
    for (int q = 0; q < 2; ++q)
#pragma unroll
      for (int a = 0; a < 8; ++a) {
        int base = 32*q + 8*(a >> 1) + 2*(a & 1) + 4*h2;
        float2 bv = *(const float2*)(b1f + base);
        float2 ui0 = *(const float2*)(uI0 + q*16 + 2*a);
        float2 ui1 = *(const float2*)(uI1 + q*16 + 2*a);
        float uj0 = u_j.s[q*16 + 2*a], uj1 = u_j.s[q*16 + 2*a + 1];
        acc[0][q][2*a]   = bv.x + ui0.x + uj0;
        acc[0][q][2*a+1] = bv.y + ui0.y + uj1;
        acc[1][q][2*a]   = bv.x + ui1.x + uj0;
        acc[1][q][2*a+1] = bv.y + ui1.y + uj1;
      }
    // layer 1 (factored): K=192 = 6 octet-steps x {absdiff, prod}
#pragma unroll
    for (int t = 0; t < 6; ++t) {
      MEMFENCE;                                // partition loads: <=4 weight frags live
      f16x8 ad0 = *(const f16x8*)(wfr + (((t  )*2+0)*64 + lane)*4);
      f16x8 ad1_ = *(const f16x8*)(wfr + (((t  )*2+1)*64 + lane)*4);
      f16x8 ap0 = *(const f16x8*)(wfr + (((t+6)*2+0)*64 + lane)*4);
      f16x8 ap1 = *(const f16x8*)(wfr + (((t+6)*2+1)*64 + lane)*4);
      f16x8 hj8 = hjr[t];
#pragma unroll
      for (int m = 0; m < 2; ++m) {
        f16x8 hi8 = *(const f16x8*)((m ? hi1 : hi0) + 16*t + 8*h2);   // broadcast read
        f16x8 di = habs8(hi8 - hj8);
        f16x8 prd = hi8 * hj8;
        __builtin_amdgcn_s_setprio(1);
        acc[m][0] = __builtin_amdgcn_mfma_f32_32x32x16_f16(ad0, di,  acc[m][0], 0,0,0);
        acc[m][1] = __builtin_amdgcn_mfma_f32_32x32x16_f16(ad1_, di, acc[m][1], 0,0,0);
        acc[m][0] = __builtin_amdgcn_mfma_f32_32x32x16_f16(ap0, prd, acc[m][0], 0,0,0);
        acc[m][1] = __builtin_amdgcn_mfma_f32_32x32x16_f16(ap1, prd, acc[m][1], 0,0,0);
        __builtin_amdgcn_s_setprio(0);
      }
    }
#pragma unroll
    for (int m = 0; m < 2; ++m) {
      MEMFENCE;
      // pack + packed-prelu the 32 z1 values, then permlane-swap h2 halves -> layer-2 B-frags
      u32 w[16];
#pragma unroll
      for (int q = 0; q < 2; ++q)
#pragma unroll
        for (int a = 0; a < 8; ++a) {
          f16x2 pz = pkrtz(acc[m][q][2*a], acc[m][q][2*a+1]);
          pz = __builtin_elementwise_max(pz, pz * a1v);
          C2 cv; cv.h = pz; w[q*8 + a] = cv.u;
        }
#pragma unroll
      for (int g = 0; g < 4; ++g) {
        plswap(w[g*4+0], w[g*4+2]);
        plswap(w[g*4+1], w[g*4+3]);
      }
      // layer 2 (swapped): zacc init = f32 bias from LDS, then 8 MFMAs
      f32x16 zacc[2];
#pragma unroll
      for (int q = 0; q < 2; ++q)
#pragma unroll
        for (int a = 0; a < 8; ++a) {
          int base = 32*q + 8*(a >> 1) + 2*(a & 1) + 4*h2;
          float2 bv = *(const float2*)(b2f + base);
          zacc[q][2*a] = bv.x; zacc[q][2*a+1] = bv.y;
        }
#pragma unroll
      for (int t2 = 0; t2 < 4; ++t2) {
        MEMFENCE;                              // keep Wd2 frags per-step (window 2)
        H8 zf; zf.u[0] = w[4*t2]; zf.u[1] = w[4*t2+1]; zf.u[2] = w[4*t2+2]; zf.u[3] = w[4*t2+3];
        f16x8 w20 = *(const f16x8*)(w2a + ((t2*2+0)*64 + lane)*4);
        f16x8 w21 = *(const f16x8*)(w2a + ((t2*2+1)*64 + lane)*4);
        __builtin_amdgcn_s_setprio(1);
        zacc[0] = __builtin_amdgcn_mfma_f32_32x32x16_f16(w20, zf.h, zacc[0], 0,0,0);
        zacc[1] = __builtin_amdgcn_mfma_f32_32x32x16_f16(w21, zf.h, zacc[1], 0,0,0);
        __builtin_amdgcn_s_setprio(0);
      }
      // final: prelu(z2) . W3 (packed pairs from LDS, broadcast) — two 8-deep fdot2 chains
      float s0 = 0.f, s1 = 0.f;
#pragma unroll
      for (int a = 0; a < 8; ++a) {
        C2 wv0; wv0.u = w3l[(h2 << 4) | a];
        f16x2 pz0 = pkrtz(zacc[0][2*a], zacc[0][2*a+1]);
        pz0 = __builtin_elementwise_max(pz0, pz0 * a2v);
        s0 = fdot2a(pz0, wv0.h, s0);
        C2 wv1; wv1.u = w3l[(h2 << 4) | 8 | a];
        f16x2 pz1 = pkrtz(zacc[1][2*a], zacc[1][2*a+1]);
        pz1 = __builtin_elementwise_max(pz1, pz1 * a2v);
        s1 = fdot2a(pz1, wv1.h, s1);
      }
      float ssum = s0 + s1;
      ssum += __shfl_xor(ssum, 32);
      int gi = I*32 + i0 + m;
      if (h2 == 0 && gi < gj && gj < NN) {
        int eo = bofs + gi*(799 - gi)/2 + (gj - gi - 1);
        out[eo] = ssum + b3;
      }
    }
  }
}

extern "C" void kernel_launch(void* const* d_in, const int* in_sizes, int n_in,
                              void* d_out, int out_size, void* d_ws, size_t ws_size,
                              hipStream_t stream) {
  const float* nf  = (const float*)d_in[1];
  const float* sc  = (const float*)d_in[2];
  const float* sm  = (const float*)d_in[3];
  const float* ss  = (const float*)d_in[4];
  const float* We1 = (const float*)d_in[5];
  const float* be1 = (const float*)d_in[6];
  const float* ae1 = (const float*)d_in[7];
  const float* We2 = (const float*)d_in[8];
  const float* be2 = (const float*)d_in[9];
  const float* ae2 = (const float*)d_in[10];
  const float* W1  = (const float*)d_in[11];
  const float* b1  = (const float*)d_in[12];
  const float* a1  = (const float*)d_in[13];
  const float* W2  = (const float*)d_in[14];
  const float* b2  = (const float*)d_in[15];
  const float* a2  = (const float*)d_in[16];
  const float* W3  = (const float*)d_in[17];
  const float* b3  = (const float*)d_in[18];
  float* out = (float*)d_out;

  char* ws = (char*)d_ws;
  float* mpart = (float*)ws;                             // 256 f32 = 1,024 B
  f16*   hbuf = (f16*)(ws + 1024);                       // 1,228,800 B
  u32*   wq   = (u32*)(ws + 1024 + 1228800);             // 143,360 B
  float* ubuf = (float*)(ws + 1024 + 1228800 + 143360);  // 1,638,400 B

  prep_mean_kernel<<<396, 256, 0, stream>>>(We1, We2, W1, W2, sc, wq, mpart);
  enc_kernel<<<200, 256, 0, stream>>>(sc, nf, sm, ss, be1, ae1, be2, ae2,
                                      mpart, wq, hbuf, ubuf);
  decoder_kernel<<<BATCH*NPAIRS, 256, 0, stream>>>(hbuf, wq, b1, b2, a1, a2,
                                                   W3, b3, ubuf, out);
}